// Round 3
// baseline (287.856 us; speedup 1.0000x reference)
//
#include <hip/hip_runtime.h>

// WaveletFeatureAugmentation via composite linear map:
//   aug = W @ wavedec9(x) + b  ==  CM @ x + b,  CM = W @ M  (M = 9-level db4
//   approx cascade as a 14x4096 matrix, pywt 'symmetric' mode).
// Kernel 1 builds CM[14][4096] in d_ws by applying the ADJOINT cascade to each
// row of W (transpose of the round-1-verified forward formula).
// Kernel 2 streams x: passthrough + 14 register-resident dots per row.

#define ROWS 16384          // 32*512
#define N0   4096
#define OUTW 4110           // 4096 + 14

__device__ __constant__ float c_dlo[8] = {
    -0.010597401784997278f,  0.032883011666982945f,
     0.030841381835986965f, -0.18703481171888114f,
    -0.02798376941698385f,   0.6308807679295904f,
     0.7148465705525415f,    0.23037781330885523f};

// Forward (verified round 1): y[i] = sum_k d[k] * a[s_n(2i+1-k)], i in [0,nout)
//   s_n(t) = t<0 ? -1-t : (t>=n ? 2n-1-t : t)
// Adjoint gather: h[s] = C(s) + [s<=5]C(-1-s) + [s>=2(n-nout)]C(2n-1-s)
//   C(t) = sum over i in [max(0,floor(t/2)), min(nout-1,floor((t+6)/2))]
//          of g[i] * d[2i+1-t]
__device__ __forceinline__ float adj_contrib(const float* __restrict__ g,
                                             int t, int nout) {
    int i0 = t >> 1;        if (i0 < 0) i0 = 0;
    int i1 = (t + 6) >> 1;  if (i1 > nout - 1) i1 = nout - 1;
    float acc = 0.f;
    for (int i = i0; i <= i1; ++i)
        acc = fmaf(g[i], c_dlo[2 * i + 1 - t], acc);
    return acc;
}

__global__ __launch_bounds__(256) void build_cm_kernel(
    const float* __restrict__ W, float* __restrict__ cm)
{
    __shared__ float A[4096];
    __shared__ float B[2051];
    const int o = blockIdx.x, tid = threadIdx.x;
    if (tid < 14) B[tid] = W[o * 14 + tid];
    __syncthreads();
    // forward lengths: 4096 ->2051 ->1029 ->518 ->262 ->134 ->70 ->38 ->22 ->14
    const int ns[10] = {14, 22, 38, 70, 134, 262, 518, 1029, 2051, 4096};
    float* g = B;   // holds gradient at length ns[lev-1]
    float* h = A;
    for (int lev = 1; lev <= 9; ++lev) {
        const int n = ns[lev], nout = ns[lev - 1];
        const int s2 = 2 * (n - nout);
        for (int s = tid; s < n; s += 256) {
            float v = adj_contrib(g, s, nout);
            if (s <= 5)  v += adj_contrib(g, -1 - s, nout);
            if (s >= s2) v += adj_contrib(g, 2 * n - 1 - s, nout);
            h[s] = v;
        }
        __syncthreads();
        float* t2 = g; g = h; h = t2;
    }
    // after 9 swaps g == A, holds 4096 coefficients = CM row o
    for (int c = tid; c < 4096; c += 256) cm[o * 4096 + c] = g[c];
}

// Main: 1024 threads/block, thread t owns cols [4t,4t+4); block does 16 rows.
// CM fragment (14 float4) stays in registers for the whole block.
__global__ __launch_bounds__(1024) void wavelet_aug_main(
    const float* __restrict__ x, const float* __restrict__ cm,
    const float* __restrict__ b, float* __restrict__ out)
{
    __shared__ float parts[2][16][14];
    const int tid  = threadIdx.x;
    const int wave = tid >> 6;
    const int lane = tid & 63;
    const int c4   = tid << 2;

    float4 cmv[14];
    #pragma unroll
    for (int o = 0; o < 14; ++o)
        cmv[o] = *reinterpret_cast<const float4*>(cm + o * N0 + c4);
    const float bb = (tid < 14) ? b[tid] : 0.f;

    const int row0 = blockIdx.x * 16;
    const float* xrow = x + (size_t)row0 * N0 + c4;

    float4 xa = *reinterpret_cast<const float4*>(xrow);   // row r=0
    for (int r = 0; r < 16; ++r) {
        float4 xb;
        if (r < 15) xb = *reinterpret_cast<const float4*>(xrow + (r + 1) * N0);

        // passthrough (out rows only 8B-aligned -> float2 stores)
        float* orow = out + (size_t)(row0 + r) * OUTW + c4;
        reinterpret_cast<float2*>(orow)[0] = make_float2(xa.x, xa.y);
        reinterpret_cast<float2*>(orow)[1] = make_float2(xa.z, xa.w);

        // per-thread partial dots
        float acc[14];
        #pragma unroll
        for (int o = 0; o < 14; ++o) {
            float v = xa.x * cmv[o].x;
            v = fmaf(xa.y, cmv[o].y, v);
            v = fmaf(xa.z, cmv[o].z, v);
            v = fmaf(xa.w, cmv[o].w, v);
            acc[o] = v;
        }
        // wave butterfly reduce (64 lanes)
        #pragma unroll
        for (int o = 0; o < 14; ++o) {
            float v = acc[o];
            v += __shfl_xor(v, 1);  v += __shfl_xor(v, 2);
            v += __shfl_xor(v, 4);  v += __shfl_xor(v, 8);
            v += __shfl_xor(v, 16); v += __shfl_xor(v, 32);
            acc[o] = v;
        }
        if (lane == 0) {
            #pragma unroll
            for (int o = 0; o < 14; ++o) parts[r & 1][wave][o] = acc[o];
        }
        __syncthreads();
        if (tid < 14) {
            float s = bb;
            #pragma unroll
            for (int w = 0; w < 16; ++w) s += parts[r & 1][w][tid];
            out[(size_t)(row0 + r) * OUTW + N0 + tid] = s;
        }
        xa = xb;
    }
}

extern "C" void kernel_launch(void* const* d_in, const int* in_sizes, int n_in,
                              void* d_out, int out_size, void* d_ws, size_t ws_size,
                              hipStream_t stream) {
    const float* x = (const float*)d_in[0];   // [32,512,4096]
    const float* W = (const float*)d_in[1];   // [14,14]
    const float* b = (const float*)d_in[2];   // [14]
    float* out = (float*)d_out;               // [32,512,4110]
    float* cm  = (float*)d_ws;                // [14][4096] composite matrix

    build_cm_kernel<<<14, 256, 0, stream>>>(W, cm);
    wavelet_aug_main<<<ROWS / 16, 1024, 0, stream>>>(x, cm, b, out);
}